// Round 4
// baseline (468.164 us; speedup 1.0000x reference)
//
#include <hip/hip_runtime.h>
#include <hip/hip_bf16.h>

// Problem: B=1024, S=64, E=256, H=512, V=128, C=32
#define BB 1024
#define SS 64
#define EE 256
#define HH 512
#define VV 128
#define CC 32

typedef _Float16 f16;
typedef _Float16 f16x8 __attribute__((ext_vector_type(8)));
typedef float    f32x4 __attribute__((ext_vector_type(4)));

// ---------------------------------------------------------------------------
// P[v][h] = emb[v,:] . W_ih[h,:] + b_ih[h] + b_hh[h]  (f16 output table)
// ---------------------------------------------------------------------------
__global__ __launch_bounds__(256) void prep_P(
    const float* __restrict__ emb, const float* __restrict__ W_ih,
    const float* __restrict__ b_ih, const float* __restrict__ b_hh,
    f16* __restrict__ P)
{
    __shared__ float er[EE];
    const int v = blockIdx.x;
    for (int i = threadIdx.x; i < EE; i += 256) er[i] = emb[(size_t)v * EE + i];
    __syncthreads();
    for (int h = threadIdx.x; h < HH; h += 256) {
        const float4* wr = (const float4*)(W_ih + (size_t)h * EE);
        float s = 0.f;
        #pragma unroll 4
        for (int e4 = 0; e4 < EE / 4; ++e4) {
            float4 w = wr[e4];
            const float* e = er + e4 * 4;
            s += w.x * e[0] + w.y * e[1] + w.z * e[2] + w.w * e[3];
        }
        P[(size_t)v * HH + h] = (f16)(s + b_ih[h] + b_hh[h]);
    }
}

// ---------------------------------------------------------------------------
// Fused RNN + MLP head. 64 blocks x 256 threads (4 waves, 1 wave/SIMD,
// VGPR cap 512/wave). Block owns 16 batch rows, computes ALL 512 h-cols
// (zero inter-block traffic). Wave w owns cols [128w, 128w+128) = 8 N-tiles.
// W_hh split: k 0..383 in registers (bfr[8][12] = 384 VGPR/lane;
// 4 waves x 64 lanes x 384 x 4B = 384 KB/CU), k 384..511 in static LDS
// (128 KB, lane-linear => conflict-free ds_read_b128).
// P is added in the epilogue via scattered L2-hot ushort loads (no LDS tile).
// After the 64-step loop the same block runs MLP1 (W1 streamed from L2) and
// the logits GEMM, writing d_out directly.
// ---------------------------------------------------------------------------
#define KSREG 12           // k-steps (of 32) held in registers
#define KSLDS 4            // k-steps held in LDS
#define NT    8            // N-tiles (16 cols) per wave
#define HSTR  520          // hbuf stride in f16 (1040 B: 16B-aligned, +4-bank skew)

__global__ __launch_bounds__(256, 1) void rnn_fused(
    const int* __restrict__ x_in, const int* __restrict__ x_lens,
    const float* __restrict__ W_hh, const f16* __restrict__ P,
    const float* __restrict__ W1, const float* __restrict__ b1,
    const float* __restrict__ W2, const float* __restrict__ b2,
    f16* __restrict__ last, float* __restrict__ out)
{
    __shared__ __align__(16) f16 hbuf[16 * HSTR];               // 16.6 KB
    __shared__ __align__(16) f16 wlds[4 * NT * KSLDS * 64 * 8]; // 128 KB
    __shared__ int xin[16 * SS];                                // 4 KB
    // total 151.8 KB static LDS (gfx950 allows 160 KB/workgroup)

    const int tid  = threadIdx.x;
    const int r0   = blockIdx.x * 16;
    const int wave = tid >> 6;       // 0..3 -> cols [128w, 128w+128)
    const int lane = tid & 63;
    const int lrow = lane & 15;      // A-row / B-col / C-col within tile
    const int quad = lane >> 4;
    const int n0w  = wave * 128;

    // ---- one-time: W_hh -> register + LDS fragments (f32->f16) ----
    // B[k][n] = W_hh[n][k]; lane holds n = lrow(+16t+n0w), k = 32ks + 8quad + j
    f16x8 bfr[NT][KSREG];
    #pragma unroll
    for (int t = 0; t < NT; ++t) {
        const float* wr = W_hh + (size_t)(n0w + 16 * t + lrow) * HH + quad * 8;
        #pragma unroll
        for (int ks = 0; ks < KSREG; ++ks) {
            float4 x0 = *(const float4*)(wr + ks * 32);
            float4 x1 = *(const float4*)(wr + ks * 32 + 4);
            f16x8 b;
            b[0] = (f16)x0.x; b[1] = (f16)x0.y; b[2] = (f16)x0.z; b[3] = (f16)x0.w;
            b[4] = (f16)x1.x; b[5] = (f16)x1.y; b[6] = (f16)x1.z; b[7] = (f16)x1.w;
            bfr[t][ks] = b;
        }
        #pragma unroll
        for (int ksl = 0; ksl < KSLDS; ++ksl) {
            float4 x0 = *(const float4*)(wr + (KSREG + ksl) * 32);
            float4 x1 = *(const float4*)(wr + (KSREG + ksl) * 32 + 4);
            f16x8 b;
            b[0] = (f16)x0.x; b[1] = (f16)x0.y; b[2] = (f16)x0.z; b[3] = (f16)x0.w;
            b[4] = (f16)x1.x; b[5] = (f16)x1.y; b[6] = (f16)x1.z; b[7] = (f16)x1.w;
            *(f16x8*)(wlds + ((((wave * NT + t) * KSLDS + ksl) * 64 + lane) << 3)) = b;
        }
    }

    // ---- LDS init: h_0 = 0, token tile; per-lane row lengths ----
    for (int i = tid; i < 16 * HSTR; i += 256) hbuf[i] = (f16)0.f;
    ((int4*)xin)[tid] = ((const int4*)(x_in + (size_t)r0 * SS))[tid];
    int lens_r[4];
    #pragma unroll
    for (int r = 0; r < 4; ++r) lens_r[r] = x_lens[r0 + quad * 4 + r];
    __syncthreads();

    const f16* arow = hbuf + lrow * HSTR + quad * 8;

    for (int st = 0; st < SS; ++st) {
        // ---- MFMA: 16 rows x 128 cols/wave, K = 512 ----
        f32x4 acc[NT];
        #pragma unroll
        for (int t = 0; t < NT; ++t) acc[t] = (f32x4){0.f, 0.f, 0.f, 0.f};
        #pragma unroll
        for (int ks = 0; ks < KSREG; ++ks) {
            f16x8 a = *(const f16x8*)(arow + ks * 32);
            #pragma unroll
            for (int t = 0; t < NT; ++t)
                acc[t] = __builtin_amdgcn_mfma_f32_16x16x32_f16(a, bfr[t][ks], acc[t], 0, 0, 0);
        }
        #pragma unroll
        for (int ksl = 0; ksl < KSLDS; ++ksl) {
            f16x8 a = *(const f16x8*)(arow + (KSREG + ksl) * 32);
            #pragma unroll
            for (int t = 0; t < NT; ++t) {
                f16x8 b = *(const f16x8*)(wlds + ((((wave * NT + t) * KSLDS + ksl) * 64 + lane) << 3));
                acc[t] = __builtin_amdgcn_mfma_f32_16x16x32_f16(a, b, acc[t], 0, 0, 0);
            }
        }

        __syncthreads();  // all waves done reading hbuf for this step

        // ---- P gather (L2-hot, C-layout scattered) ----
        f16 pv[NT][4];
        #pragma unroll
        for (int r = 0; r < 4; ++r) {
            const int tok = xin[(quad * 4 + r) * SS + st];
            const f16* pb = P + (size_t)tok * HH + n0w + lrow;
            #pragma unroll
            for (int t = 0; t < NT; ++t) pv[t][r] = pb[16 * t];
        }

        // ---- epilogue: h = tanh(acc + P); C layout col=lrow+16t, row=quad*4+r
        const int tp1 = st + 1;
        #pragma unroll
        for (int t = 0; t < NT; ++t) {
            const int col = n0w + 16 * t + lrow;
            #pragma unroll
            for (int r = 0; r < 4; ++r) {
                const int row = quad * 4 + r;
                float z = acc[t][r] + (float)pv[t][r];
                float e = __expf(2.f * z);      // saturates correctly at +-inf
                f16 h16 = (f16)(1.f - 2.f / (e + 1.f));
                hbuf[row * HSTR + col] = h16;
                if (lens_r[r] == tp1)
                    last[(size_t)(r0 + row) * HH + col] = h16;
            }
        }

        __syncthreads();  // hbuf fully written before next step's reads
    }

    // ======================= MLP head (fused tail) =========================
    // 'last' rows for this block are complete; the final __syncthreads drained
    // vmcnt, and these lines were never read into L1 -> safe to load back.
    for (int i = tid; i < 16 * (HH / 8); i += 256) {
        const int row = i >> 6;
        const int c8  = (i & 63) * 8;
        *(float4*)(hbuf + row * HSTR + c8) =
            *(const float4*)(last + (size_t)(r0 + row) * HH + c8);
    }
    __syncthreads();

    // ---- MLP1: hidden = relu(last @ W1^T + b1), W1 streamed from L2 ----
    {
        f32x4 macc[NT];
        #pragma unroll
        for (int t = 0; t < NT; ++t) macc[t] = (f32x4){0.f, 0.f, 0.f, 0.f};
        #pragma unroll
        for (int ks = 0; ks < 16; ++ks) {
            f16x8 a = *(const f16x8*)(arow + ks * 32);
            #pragma unroll
            for (int t = 0; t < NT; ++t) {
                const float* wr = W1 + (size_t)(n0w + 16 * t + lrow) * HH + quad * 8 + ks * 32;
                float4 x0 = *(const float4*)(wr);
                float4 x1 = *(const float4*)(wr + 4);
                f16x8 b;
                b[0] = (f16)x0.x; b[1] = (f16)x0.y; b[2] = (f16)x0.z; b[3] = (f16)x0.w;
                b[4] = (f16)x1.x; b[5] = (f16)x1.y; b[6] = (f16)x1.z; b[7] = (f16)x1.w;
                macc[t] = __builtin_amdgcn_mfma_f32_16x16x32_f16(a, b, macc[t], 0, 0, 0);
            }
        }
        __syncthreads();  // done reading hbuf; wlds is dead -> reuse as hidden
        #pragma unroll
        for (int t = 0; t < NT; ++t) {
            const int col = n0w + 16 * t + lrow;
            const float bb = b1[col];
            #pragma unroll
            for (int r = 0; r < 4; ++r) {
                const int row = quad * 4 + r;
                wlds[row * HSTR + col] = (f16)fmaxf(macc[t][r] + bb, 0.f);
            }
        }
    }
    __syncthreads();

    // ---- logits = hidden @ W2^T + b2 (16x32, K=512): waves 0,1 ----
    if (wave < 2) {
        f32x4 lacc = {0.f, 0.f, 0.f, 0.f};
        const f16* hrow = wlds + lrow * HSTR + quad * 8;
        const float* wr2 = W2 + (size_t)(wave * 16 + lrow) * HH + quad * 8;
        #pragma unroll
        for (int ks = 0; ks < 16; ++ks) {
            f16x8 a = *(const f16x8*)(hrow + ks * 32);
            float4 x0 = *(const float4*)(wr2 + ks * 32);
            float4 x1 = *(const float4*)(wr2 + ks * 32 + 4);
            f16x8 b;
            b[0] = (f16)x0.x; b[1] = (f16)x0.y; b[2] = (f16)x0.z; b[3] = (f16)x0.w;
            b[4] = (f16)x1.x; b[5] = (f16)x1.y; b[6] = (f16)x1.z; b[7] = (f16)x1.w;
            lacc = __builtin_amdgcn_mfma_f32_16x16x32_f16(a, b, lacc, 0, 0, 0);
        }
        const int col = wave * 16 + lrow;
        const float bb = b2[col];
        #pragma unroll
        for (int r = 0; r < 4; ++r) {
            const int row = quad * 4 + r;
            out[(size_t)(r0 + row) * CC + col] = lacc[r] + bb;
        }
    }
}

// ---------------------------------------------------------------------------
extern "C" void kernel_launch(void* const* d_in, const int* in_sizes, int n_in,
                              void* d_out, int out_size, void* d_ws, size_t ws_size,
                              hipStream_t stream)
{
    const int*   x_in   = (const int*)d_in[0];
    const int*   x_lens = (const int*)d_in[1];
    const float* emb    = (const float*)d_in[2];
    const float* W_ih   = (const float*)d_in[3];
    const float* b_ih   = (const float*)d_in[4];
    const float* W_hh   = (const float*)d_in[5];
    const float* b_hh   = (const float*)d_in[6];
    const float* W1     = (const float*)d_in[7];
    const float* b1     = (const float*)d_in[8];
    const float* W2     = (const float*)d_in[9];
    const float* b2     = (const float*)d_in[10];
    float* out = (float*)d_out;

    // workspace carve (re-poisoned every launch; everything rewritten below)
    char* ws = (char*)d_ws;
    f16* P    = (f16*)ws;                 // 128 KiB (slot 256 KiB)
    f16* last = (f16*)(ws + (256 << 10)); // 1 MiB

    hipLaunchKernelGGL(prep_P, dim3(VV), dim3(256), 0, stream,
                       emb, W_ih, b_ih, b_hh, P);
    hipLaunchKernelGGL(rnn_fused, dim3(BB / 16), dim3(256), 0, stream,
                       x_in, x_lens, W_hh, P, W1, b1, W2, b2, last, out);
}

// Round 5
// 460.206 us; speedup vs baseline: 1.0173x; 1.0173x over previous
//
#include <hip/hip_runtime.h>
#include <hip/hip_bf16.h>

// Problem: B=1024, S=64, E=256, H=512, V=128, C=32
#define BB 1024
#define SS 64
#define EE 256
#define HH 512
#define VV 128
#define CC 32

typedef _Float16 f16;
typedef _Float16 f16x8 __attribute__((ext_vector_type(8)));
typedef float    f32x4 __attribute__((ext_vector_type(4)));

// ---------------------------------------------------------------------------
// P[v][h] = emb[v,:] . W_ih[h,:] + b_ih[h] + b_hh[h]  (f16 output table)
// ---------------------------------------------------------------------------
__global__ __launch_bounds__(256) void prep_P(
    const float* __restrict__ emb, const float* __restrict__ W_ih,
    const float* __restrict__ b_ih, const float* __restrict__ b_hh,
    f16* __restrict__ P)
{
    __shared__ float er[EE];
    const int v = blockIdx.x;
    for (int i = threadIdx.x; i < EE; i += 256) er[i] = emb[(size_t)v * EE + i];
    __syncthreads();
    for (int h = threadIdx.x; h < HH; h += 256) {
        const float4* wr = (const float4*)(W_ih + (size_t)h * EE);
        float s = 0.f;
        #pragma unroll 4
        for (int e4 = 0; e4 < EE / 4; ++e4) {
            float4 w = wr[e4];
            const float* e = er + e4 * 4;
            s += w.x * e[0] + w.y * e[1] + w.z * e[2] + w.w * e[3];
        }
        P[(size_t)v * HH + h] = (f16)(s + b_ih[h] + b_hh[h]);
    }
}

// ---------------------------------------------------------------------------
// Fused RNN + MLP head. 64 blocks x 256 threads (4 waves, 1 wave/SIMD).
// Block owns 16 batch rows, computes ALL 512 h-cols (zero inter-block
// traffic). Wave w owns cols [128w, 128w+128) = 8 N-tiles.
// W_hh three-way split per lane (gfx950: 256 arch VGPR + 256 AGPR/wave):
//   ks 0..7   -> AGPRs (8 ks x 8 t x 4 regs = 256 AGPR; pinned via "+a" asm;
//                MFMA reads AGPR operands natively, no copies)
//   ks 8..12  -> arch VGPRs (5 x 8 x 4 = 160 regs)
//   ks 13..15 -> static LDS slab (96 KB, lane-linear, conflict-free b128)
// P added in the epilogue via scattered L2-hot ushort loads. MLP1 + logits
// run as a fused tail in the same block (W1/W2 streamed from L2).
// ---------------------------------------------------------------------------
#define KSA   8            // k-steps in AGPRs
#define KSV   5            // k-steps in arch VGPRs
#define KSLDS 3            // k-steps in LDS
#define NT    8            // N-tiles (16 cols) per wave
#define HSTR  520          // hbuf stride in f16 (1040 B: 16B-aligned, +4-bank skew)

__global__ __launch_bounds__(256, 1) void rnn_fused(
    const int* __restrict__ x_in, const int* __restrict__ x_lens,
    const float* __restrict__ W_hh, const f16* __restrict__ P,
    const float* __restrict__ W1, const float* __restrict__ b1,
    const float* __restrict__ W2, const float* __restrict__ b2,
    f16* __restrict__ last, float* __restrict__ out)
{
    __shared__ __align__(16) f16 hbuf[16 * HSTR];                // 16.6 KB
    __shared__ __align__(16) f16 wlds[4 * NT * KSLDS * 64 * 8];  // 96 KB
    __shared__ int xin[16 * SS];                                 // 4 KB

    const int tid  = threadIdx.x;
    const int r0   = blockIdx.x * 16;
    const int wave = tid >> 6;       // 0..3 -> cols [128w, 128w+128)
    const int lane = tid & 63;
    const int lrow = lane & 15;      // A-row / B-col / C-col within tile
    const int quad = lane >> 4;
    const int n0w  = wave * 128;

    // ---- one-time: W_hh -> AGPR + VGPR + LDS fragments (f32->f16) ----
    // B[k][n] = W_hh[n][k]; lane holds n = lrow(+16t+n0w), k = 32ks + 8quad + j
    f16x8 bA[NT][KSA];   // pinned to AGPRs
    f16x8 bV[NT][KSV];   // arch VGPRs
    #pragma unroll
    for (int t = 0; t < NT; ++t) {
        const float* wr = W_hh + (size_t)(n0w + 16 * t + lrow) * HH + quad * 8;
        #pragma unroll
        for (int ks = 0; ks < KSA; ++ks) {
            float4 x0 = *(const float4*)(wr + ks * 32);
            float4 x1 = *(const float4*)(wr + ks * 32 + 4);
            f16x8 b;
            b[0] = (f16)x0.x; b[1] = (f16)x0.y; b[2] = (f16)x0.z; b[3] = (f16)x0.w;
            b[4] = (f16)x1.x; b[5] = (f16)x1.y; b[6] = (f16)x1.z; b[7] = (f16)x1.w;
            asm volatile("" : "+a"(b));   // pin this value into the AGPR file
            bA[t][ks] = b;
        }
        #pragma unroll
        for (int ks = 0; ks < KSV; ++ks) {
            float4 x0 = *(const float4*)(wr + (KSA + ks) * 32);
            float4 x1 = *(const float4*)(wr + (KSA + ks) * 32 + 4);
            f16x8 b;
            b[0] = (f16)x0.x; b[1] = (f16)x0.y; b[2] = (f16)x0.z; b[3] = (f16)x0.w;
            b[4] = (f16)x1.x; b[5] = (f16)x1.y; b[6] = (f16)x1.z; b[7] = (f16)x1.w;
            bV[t][ks] = b;
        }
        #pragma unroll
        for (int ksl = 0; ksl < KSLDS; ++ksl) {
            float4 x0 = *(const float4*)(wr + (KSA + KSV + ksl) * 32);
            float4 x1 = *(const float4*)(wr + (KSA + KSV + ksl) * 32 + 4);
            f16x8 b;
            b[0] = (f16)x0.x; b[1] = (f16)x0.y; b[2] = (f16)x0.z; b[3] = (f16)x0.w;
            b[4] = (f16)x1.x; b[5] = (f16)x1.y; b[6] = (f16)x1.z; b[7] = (f16)x1.w;
            *(f16x8*)(wlds + ((((wave * NT + t) * KSLDS + ksl) * 64 + lane) << 3)) = b;
        }
    }

    // ---- LDS init: h_0 = 0, token tile; per-lane row lengths ----
    for (int i = tid; i < 16 * HSTR; i += 256) hbuf[i] = (f16)0.f;
    ((int4*)xin)[tid] = ((const int4*)(x_in + (size_t)r0 * SS))[tid];
    int lens_r[4];
    #pragma unroll
    for (int r = 0; r < 4; ++r) lens_r[r] = x_lens[r0 + quad * 4 + r];
    __syncthreads();

    const f16* arow = hbuf + lrow * HSTR + quad * 8;

    for (int st = 0; st < SS; ++st) {
        // ---- MFMA: 16 rows x 128 cols/wave, K = 512 ----
        f32x4 acc[NT];
        #pragma unroll
        for (int t = 0; t < NT; ++t) acc[t] = (f32x4){0.f, 0.f, 0.f, 0.f};
        #pragma unroll
        for (int ks = 0; ks < KSA; ++ks) {
            f16x8 a = *(const f16x8*)(arow + ks * 32);
            #pragma unroll
            for (int t = 0; t < NT; ++t)
                acc[t] = __builtin_amdgcn_mfma_f32_16x16x32_f16(a, bA[t][ks], acc[t], 0, 0, 0);
        }
        #pragma unroll
        for (int ks = 0; ks < KSV; ++ks) {
            f16x8 a = *(const f16x8*)(arow + (KSA + ks) * 32);
            #pragma unroll
            for (int t = 0; t < NT; ++t)
                acc[t] = __builtin_amdgcn_mfma_f32_16x16x32_f16(a, bV[t][ks], acc[t], 0, 0, 0);
        }
        #pragma unroll
        for (int ksl = 0; ksl < KSLDS; ++ksl) {
            f16x8 a = *(const f16x8*)(arow + (KSA + KSV + ksl) * 32);
            #pragma unroll
            for (int t = 0; t < NT; ++t) {
                f16x8 b = *(const f16x8*)(wlds + ((((wave * NT + t) * KSLDS + ksl) * 64 + lane) << 3));
                acc[t] = __builtin_amdgcn_mfma_f32_16x16x32_f16(a, b, acc[t], 0, 0, 0);
            }
        }

        __syncthreads();  // all waves done reading hbuf for this step

        // ---- P gather (L2-hot, C-layout scattered) ----
        f16 pv[NT][4];
        #pragma unroll
        for (int r = 0; r < 4; ++r) {
            const int tok = xin[(quad * 4 + r) * SS + st];
            const f16* pb = P + (size_t)tok * HH + n0w + lrow;
            #pragma unroll
            for (int t = 0; t < NT; ++t) pv[t][r] = pb[16 * t];
        }

        // ---- epilogue: h = tanh(acc + P); C layout col=lrow+16t, row=quad*4+r
        const int tp1 = st + 1;
        #pragma unroll
        for (int t = 0; t < NT; ++t) {
            const int col = n0w + 16 * t + lrow;
            #pragma unroll
            for (int r = 0; r < 4; ++r) {
                const int row = quad * 4 + r;
                float z = acc[t][r] + (float)pv[t][r];
                float e = __expf(2.f * z);      // saturates correctly at +-inf
                f16 h16 = (f16)(1.f - 2.f / (e + 1.f));
                hbuf[row * HSTR + col] = h16;
                if (lens_r[r] == tp1)
                    last[(size_t)(r0 + row) * HH + col] = h16;
            }
        }

        __syncthreads();  // hbuf fully written before next step's reads
    }

    // ======================= MLP head (fused tail) =========================
    // 'last' rows for this block are complete; these lines were never read
    // into this CU's caches before -> safe to load back.
    for (int i = tid; i < 16 * (HH / 8); i += 256) {
        const int row = i >> 6;
        const int c8  = (i & 63) * 8;
        *(float4*)(hbuf + row * HSTR + c8) =
            *(const float4*)(last + (size_t)(r0 + row) * HH + c8);
    }
    __syncthreads();

    // ---- MLP1: hidden = relu(last @ W1^T + b1), W1 streamed from L2 ----
    {
        f32x4 macc[NT];
        #pragma unroll
        for (int t = 0; t < NT; ++t) macc[t] = (f32x4){0.f, 0.f, 0.f, 0.f};
        #pragma unroll
        for (int ks = 0; ks < 16; ++ks) {
            f16x8 a = *(const f16x8*)(arow + ks * 32);
            #pragma unroll
            for (int t = 0; t < NT; ++t) {
                const float* wr = W1 + (size_t)(n0w + 16 * t + lrow) * HH + quad * 8 + ks * 32;
                float4 x0 = *(const float4*)(wr);
                float4 x1 = *(const float4*)(wr + 4);
                f16x8 b;
                b[0] = (f16)x0.x; b[1] = (f16)x0.y; b[2] = (f16)x0.z; b[3] = (f16)x0.w;
                b[4] = (f16)x1.x; b[5] = (f16)x1.y; b[6] = (f16)x1.z; b[7] = (f16)x1.w;
                macc[t] = __builtin_amdgcn_mfma_f32_16x16x32_f16(a, b, macc[t], 0, 0, 0);
            }
        }
        __syncthreads();  // done reading hbuf; wlds is dead -> reuse as hidden
        #pragma unroll
        for (int t = 0; t < NT; ++t) {
            const int col = n0w + 16 * t + lrow;
            const float bb = b1[col];
            #pragma unroll
            for (int r = 0; r < 4; ++r) {
                const int row = quad * 4 + r;
                wlds[row * HSTR + col] = (f16)fmaxf(macc[t][r] + bb, 0.f);
            }
        }
    }
    __syncthreads();

    // ---- logits = hidden @ W2^T + b2 (16x32, K=512): waves 0,1 ----
    if (wave < 2) {
        f32x4 lacc = {0.f, 0.f, 0.f, 0.f};
        const f16* hrow = wlds + lrow * HSTR + quad * 8;
        const float* wr2 = W2 + (size_t)(wave * 16 + lrow) * HH + quad * 8;
        #pragma unroll
        for (int ks = 0; ks < 16; ++ks) {
            f16x8 a = *(const f16x8*)(hrow + ks * 32);
            float4 x0 = *(const float4*)(wr2 + ks * 32);
            float4 x1 = *(const float4*)(wr2 + ks * 32 + 4);
            f16x8 b;
            b[0] = (f16)x0.x; b[1] = (f16)x0.y; b[2] = (f16)x0.z; b[3] = (f16)x0.w;
            b[4] = (f16)x1.x; b[5] = (f16)x1.y; b[6] = (f16)x1.z; b[7] = (f16)x1.w;
            lacc = __builtin_amdgcn_mfma_f32_16x16x32_f16(a, b, lacc, 0, 0, 0);
        }
        const int col = wave * 16 + lrow;
        const float bb = b2[col];
        #pragma unroll
        for (int r = 0; r < 4; ++r) {
            const int row = quad * 4 + r;
            out[(size_t)(r0 + row) * CC + col] = lacc[r] + bb;
        }
    }
}

// ---------------------------------------------------------------------------
extern "C" void kernel_launch(void* const* d_in, const int* in_sizes, int n_in,
                              void* d_out, int out_size, void* d_ws, size_t ws_size,
                              hipStream_t stream)
{
    const int*   x_in   = (const int*)d_in[0];
    const int*   x_lens = (const int*)d_in[1];
    const float* emb    = (const float*)d_in[2];
    const float* W_ih   = (const float*)d_in[3];
    const float* b_ih   = (const float*)d_in[4];
    const float* W_hh   = (const float*)d_in[5];
    const float* b_hh   = (const float*)d_in[6];
    const float* W1     = (const float*)d_in[7];
    const float* b1     = (const float*)d_in[8];
    const float* W2     = (const float*)d_in[9];
    const float* b2     = (const float*)d_in[10];
    float* out = (float*)d_out;

    // workspace carve (re-poisoned every launch; everything rewritten below)
    char* ws = (char*)d_ws;
    f16* P    = (f16*)ws;                 // 128 KiB (slot 256 KiB)
    f16* last = (f16*)(ws + (256 << 10)); // 1 MiB

    hipLaunchKernelGGL(prep_P, dim3(VV), dim3(256), 0, stream,
                       emb, W_ih, b_ih, b_hh, P);
    hipLaunchKernelGGL(rnn_fused, dim3(BB / 16), dim3(256), 0, stream,
                       x_in, x_lens, W_hh, P, W1, b1, W2, b2, last, out);
}

// Round 6
// 459.634 us; speedup vs baseline: 1.0186x; 1.0012x over previous
//
#include <hip/hip_runtime.h>
#include <hip/hip_bf16.h>

// Problem: B=1024, S=64, E=256, H=512, V=128, C=32
#define BB 1024
#define SS 64
#define EE 256
#define HH 512
#define VV 128
#define CC 32

typedef _Float16 f16;
typedef _Float16 f16x8 __attribute__((ext_vector_type(8)));
typedef float    f32x4 __attribute__((ext_vector_type(4)));

// ---------------------------------------------------------------------------
// P[v][h] = emb[v,:] . W_ih[h,:] + b_ih[h] + b_hh[h]  (f16 table, 128x512)
// 4 vocab rows per block (32 blocks): W_ih streamed once per block.
// ---------------------------------------------------------------------------
__global__ __launch_bounds__(256) void prep_P(
    const float* __restrict__ emb, const float* __restrict__ W_ih,
    const float* __restrict__ b_ih, const float* __restrict__ b_hh,
    f16* __restrict__ P)
{
    __shared__ float er[4][EE];
    const int v0 = blockIdx.x * 4;
    for (int i = threadIdx.x; i < 4 * EE; i += 256)
        er[i >> 8][i & 255] = emb[(size_t)v0 * EE + i];
    __syncthreads();
    for (int h = threadIdx.x; h < HH; h += 256) {
        const float4* wr = (const float4*)(W_ih + (size_t)h * EE);
        float s0 = 0.f, s1 = 0.f, s2 = 0.f, s3 = 0.f;
        #pragma unroll 4
        for (int e4 = 0; e4 < EE / 4; ++e4) {
            float4 w = wr[e4];
            const float* e0 = &er[0][e4 * 4];
            const float* e1 = &er[1][e4 * 4];
            const float* e2 = &er[2][e4 * 4];
            const float* e3 = &er[3][e4 * 4];
            s0 += w.x * e0[0] + w.y * e0[1] + w.z * e0[2] + w.w * e0[3];
            s1 += w.x * e1[0] + w.y * e1[1] + w.z * e1[2] + w.w * e1[3];
            s2 += w.x * e2[0] + w.y * e2[1] + w.z * e2[2] + w.w * e2[3];
            s3 += w.x * e3[0] + w.y * e3[1] + w.z * e3[2] + w.w * e3[3];
        }
        const float bias = b_ih[h] + b_hh[h];
        P[(size_t)(v0 + 0) * HH + h] = (f16)(s0 + bias);
        P[(size_t)(v0 + 1) * HH + h] = (f16)(s1 + bias);
        P[(size_t)(v0 + 2) * HH + h] = (f16)(s2 + bias);
        P[(size_t)(v0 + 3) * HH + h] = (f16)(s3 + bias);
    }
}

// ---------------------------------------------------------------------------
// Fused RNN + MLP head. 64 blocks x 256 threads (4 waves, 1 wave/SIMD).
// Block owns 16 batch rows, computes ALL 512 h-cols (zero inter-block
// traffic). Wave w owns cols [128w, 128w+128) = 8 N-tiles.
// W_hh three-way split per lane (gfx950 unified RF: 256 arch + 256 AGPR/wave):
//   ks 0..7   -> AGPRs  (8 ks x 8 t x 4 regs = 256, pinned via "+a" asm)
//   ks 8..11  -> arch VGPRs (4 x 8 x 4 = 128 regs; leaves ~80 for acc/temps)
//   ks 12..15 -> static LDS slab (128 KB, lane-linear, conflict-free b128)
// P added in the epilogue via scattered L2-hot ushort loads. MLP1 + logits
// run as a fused tail in the same block (W1/W2 streamed from L2).
// ---------------------------------------------------------------------------
#define KSA   8            // k-steps in AGPRs
#define KSV   4            // k-steps in arch VGPRs
#define KSLDS 4            // k-steps in LDS
#define NT    8            // N-tiles (16 cols) per wave
#define HSTR  520          // hbuf stride in f16 (1040 B: 16B-aligned, +4-bank skew)

__global__ __launch_bounds__(256, 1) void rnn_fused(
    const int* __restrict__ x_in, const int* __restrict__ x_lens,
    const float* __restrict__ W_hh, const f16* __restrict__ P,
    const float* __restrict__ W1, const float* __restrict__ b1,
    const float* __restrict__ W2, const float* __restrict__ b2,
    f16* __restrict__ last, float* __restrict__ out)
{
    __shared__ __align__(16) f16 hbuf[16 * HSTR];                // 16.6 KB
    __shared__ __align__(16) f16 wlds[4 * NT * KSLDS * 64 * 8];  // 128 KB
    __shared__ int xin[16 * SS];                                 // 4 KB

    const int tid  = threadIdx.x;
    const int r0   = blockIdx.x * 16;
    const int wave = tid >> 6;       // 0..3 -> cols [128w, 128w+128)
    const int lane = tid & 63;
    const int lrow = lane & 15;      // A-row / B-col / C-col within tile
    const int quad = lane >> 4;
    const int n0w  = wave * 128;

    // ---- one-time: W_hh -> AGPR + VGPR + LDS fragments (f32->f16) ----
    // B[k][n] = W_hh[n][k]; lane holds n = lrow(+16t+n0w), k = 32ks + 8quad + j
    f16x8 bA[NT][KSA];   // pinned to AGPRs
    f16x8 bV[NT][KSV];   // arch VGPRs
    #pragma unroll
    for (int t = 0; t < NT; ++t) {
        const float* wr = W_hh + (size_t)(n0w + 16 * t + lrow) * HH + quad * 8;
        #pragma unroll
        for (int ks = 0; ks < KSA; ++ks) {
            float4 x0 = *(const float4*)(wr + ks * 32);
            float4 x1 = *(const float4*)(wr + ks * 32 + 4);
            f16x8 b;
            b[0] = (f16)x0.x; b[1] = (f16)x0.y; b[2] = (f16)x0.z; b[3] = (f16)x0.w;
            b[4] = (f16)x1.x; b[5] = (f16)x1.y; b[6] = (f16)x1.z; b[7] = (f16)x1.w;
            asm volatile("" : "+a"(b));   // pin this value into the AGPR file
            bA[t][ks] = b;
        }
        #pragma unroll
        for (int ks = 0; ks < KSV; ++ks) {
            float4 x0 = *(const float4*)(wr + (KSA + ks) * 32);
            float4 x1 = *(const float4*)(wr + (KSA + ks) * 32 + 4);
            f16x8 b;
            b[0] = (f16)x0.x; b[1] = (f16)x0.y; b[2] = (f16)x0.z; b[3] = (f16)x0.w;
            b[4] = (f16)x1.x; b[5] = (f16)x1.y; b[6] = (f16)x1.z; b[7] = (f16)x1.w;
            bV[t][ks] = b;
        }
        #pragma unroll
        for (int ksl = 0; ksl < KSLDS; ++ksl) {
            float4 x0 = *(const float4*)(wr + (KSA + KSV + ksl) * 32);
            float4 x1 = *(const float4*)(wr + (KSA + KSV + ksl) * 32 + 4);
            f16x8 b;
            b[0] = (f16)x0.x; b[1] = (f16)x0.y; b[2] = (f16)x0.z; b[3] = (f16)x0.w;
            b[4] = (f16)x1.x; b[5] = (f16)x1.y; b[6] = (f16)x1.z; b[7] = (f16)x1.w;
            *(f16x8*)(wlds + ((((wave * NT + t) * KSLDS + ksl) * 64 + lane) << 3)) = b;
        }
    }

    // ---- LDS init: h_0 = 0, token tile; per-lane row lengths ----
    for (int i = tid; i < 16 * HSTR; i += 256) hbuf[i] = (f16)0.f;
    ((int4*)xin)[tid] = ((const int4*)(x_in + (size_t)r0 * SS))[tid];
    int lens_r[4];
    #pragma unroll
    for (int r = 0; r < 4; ++r) lens_r[r] = x_lens[r0 + quad * 4 + r];
    __syncthreads();

    const f16* arow = hbuf + lrow * HSTR + quad * 8;

    #pragma unroll 1
    for (int st = 0; st < SS; ++st) {
        // ---- MFMA: 16 rows x 128 cols/wave, K = 512 ----
        f32x4 acc[NT];
        #pragma unroll
        for (int t = 0; t < NT; ++t) acc[t] = (f32x4){0.f, 0.f, 0.f, 0.f};
        #pragma unroll
        for (int ks = 0; ks < KSA; ++ks) {
            f16x8 a = *(const f16x8*)(arow + ks * 32);
            #pragma unroll
            for (int t = 0; t < NT; ++t)
                acc[t] = __builtin_amdgcn_mfma_f32_16x16x32_f16(a, bA[t][ks], acc[t], 0, 0, 0);
        }
        #pragma unroll
        for (int ks = 0; ks < KSV; ++ks) {
            f16x8 a = *(const f16x8*)(arow + (KSA + ks) * 32);
            #pragma unroll
            for (int t = 0; t < NT; ++t)
                acc[t] = __builtin_amdgcn_mfma_f32_16x16x32_f16(a, bV[t][ks], acc[t], 0, 0, 0);
        }
        #pragma unroll
        for (int ksl = 0; ksl < KSLDS; ++ksl) {
            f16x8 a = *(const f16x8*)(arow + (KSA + KSV + ksl) * 32);
            #pragma unroll
            for (int t = 0; t < NT; ++t) {
                f16x8 b = *(const f16x8*)(wlds + ((((wave * NT + t) * KSLDS + ksl) * 64 + lane) << 3));
                acc[t] = __builtin_amdgcn_mfma_f32_16x16x32_f16(a, b, acc[t], 0, 0, 0);
            }
        }

        __syncthreads();  // all waves done reading hbuf for this step

        // ---- P gather (L2-hot, C-layout scattered) ----
        f16 pv[NT][4];
        #pragma unroll
        for (int r = 0; r < 4; ++r) {
            const int tok = xin[(quad * 4 + r) * SS + st];
            const f16* pb = P + (size_t)tok * HH + n0w + lrow;
            #pragma unroll
            for (int t = 0; t < NT; ++t) pv[t][r] = pb[16 * t];
        }

        // ---- epilogue: h = tanh(acc + P); C layout col=lrow+16t, row=quad*4+r
        const int tp1 = st + 1;
        #pragma unroll
        for (int t = 0; t < NT; ++t) {
            const int col = n0w + 16 * t + lrow;
            #pragma unroll
            for (int r = 0; r < 4; ++r) {
                const int row = quad * 4 + r;
                float z = acc[t][r] + (float)pv[t][r];
                float e = __expf(2.f * z);      // saturates correctly at +-inf
                f16 h16 = (f16)(1.f - 2.f / (e + 1.f));
                hbuf[row * HSTR + col] = h16;
                if (lens_r[r] == tp1)
                    last[(size_t)(r0 + row) * HH + col] = h16;
            }
        }

        __syncthreads();  // hbuf fully written before next step's reads
    }

    // ======================= MLP head (fused tail) =========================
    // 'last' rows for this block are complete; these lines were never loaded
    // into this CU's caches before -> safe to read back.
    for (int i = tid; i < 16 * (HH / 8); i += 256) {
        const int row = i >> 6;
        const int c8  = (i & 63) * 8;
        *(float4*)(hbuf + row * HSTR + c8) =
            *(const float4*)(last + (size_t)(r0 + row) * HH + c8);
    }
    __syncthreads();

    // ---- MLP1: hidden = relu(last @ W1^T + b1), W1 streamed from L2 ----
    {
        f32x4 macc[NT];
        #pragma unroll
        for (int t = 0; t < NT; ++t) macc[t] = (f32x4){0.f, 0.f, 0.f, 0.f};
        #pragma unroll
        for (int ks = 0; ks < 16; ++ks) {
            f16x8 a = *(const f16x8*)(arow + ks * 32);
            #pragma unroll
            for (int t = 0; t < NT; ++t) {
                const float* wr = W1 + (size_t)(n0w + 16 * t + lrow) * HH + quad * 8 + ks * 32;
                float4 x0 = *(const float4*)(wr);
                float4 x1 = *(const float4*)(wr + 4);
                f16x8 b;
                b[0] = (f16)x0.x; b[1] = (f16)x0.y; b[2] = (f16)x0.z; b[3] = (f16)x0.w;
                b[4] = (f16)x1.x; b[5] = (f16)x1.y; b[6] = (f16)x1.z; b[7] = (f16)x1.w;
                macc[t] = __builtin_amdgcn_mfma_f32_16x16x32_f16(a, b, macc[t], 0, 0, 0);
            }
        }
        __syncthreads();  // done reading hbuf; wlds is dead -> reuse as hidden
        #pragma unroll
        for (int t = 0; t < NT; ++t) {
            const int col = n0w + 16 * t + lrow;
            const float bb = b1[col];
            #pragma unroll
            for (int r = 0; r < 4; ++r) {
                const int row = quad * 4 + r;
                wlds[row * HSTR + col] = (f16)fmaxf(macc[t][r] + bb, 0.f);
            }
        }
    }
    __syncthreads();

    // ---- logits = hidden @ W2^T + b2 (16x32, K=512): waves 0,1 ----
    if (wave < 2) {
        f32x4 lacc = {0.f, 0.f, 0.f, 0.f};
        const f16* hrow = wlds + lrow * HSTR + quad * 8;
        const float* wr2 = W2 + (size_t)(wave * 16 + lrow) * HH + quad * 8;
        #pragma unroll
        for (int ks = 0; ks < 16; ++ks) {
            f16x8 a = *(const f16x8*)(hrow + ks * 32);
            float4 x0 = *(const float4*)(wr2 + ks * 32);
            float4 x1 = *(const float4*)(wr2 + ks * 32 + 4);
            f16x8 b;
            b[0] = (f16)x0.x; b[1] = (f16)x0.y; b[2] = (f16)x0.z; b[3] = (f16)x0.w;
            b[4] = (f16)x1.x; b[5] = (f16)x1.y; b[6] = (f16)x1.z; b[7] = (f16)x1.w;
            lacc = __builtin_amdgcn_mfma_f32_16x16x32_f16(a, b, lacc, 0, 0, 0);
        }
        const int col = wave * 16 + lrow;
        const float bb = b2[col];
        #pragma unroll
        for (int r = 0; r < 4; ++r) {
            const int row = quad * 4 + r;
            out[(size_t)(r0 + row) * CC + col] = lacc[r] + bb;
        }
    }
}

// ---------------------------------------------------------------------------
extern "C" void kernel_launch(void* const* d_in, const int* in_sizes, int n_in,
                              void* d_out, int out_size, void* d_ws, size_t ws_size,
                              hipStream_t stream)
{
    const int*   x_in   = (const int*)d_in[0];
    const int*   x_lens = (const int*)d_in[1];
    const float* emb    = (const float*)d_in[2];
    const float* W_ih   = (const float*)d_in[3];
    const float* b_ih   = (const float*)d_in[4];
    const float* W_hh   = (const float*)d_in[5];
    const float* b_hh   = (const float*)d_in[6];
    const float* W1     = (const float*)d_in[7];
    const float* b1     = (const float*)d_in[8];
    const float* W2     = (const float*)d_in[9];
    const float* b2     = (const float*)d_in[10];
    float* out = (float*)d_out;

    // workspace carve (re-poisoned every launch; everything rewritten below)
    char* ws = (char*)d_ws;
    f16* P    = (f16*)ws;                 // 128 KiB (slot 256 KiB)
    f16* last = (f16*)(ws + (256 << 10)); // 1 MiB

    hipLaunchKernelGGL(prep_P, dim3(VV / 4), dim3(256), 0, stream,
                       emb, W_ih, b_ih, b_hh, P);
    hipLaunchKernelGGL(rnn_fused, dim3(BB / 16), dim3(256), 0, stream,
                       x_in, x_lens, W_hh, P, W1, b1, W2, b2, last, out);
}

// Round 8
// 444.798 us; speedup vs baseline: 1.0525x; 1.0334x over previous
//
#include <hip/hip_runtime.h>
#include <hip/hip_bf16.h>

// Problem: B=1024, S=64, E=256, H=512, V=128, C=32
#define BB 1024
#define SS 64
#define EE 256
#define HH 512
#define VV 128
#define CC 32

typedef _Float16 f16;
typedef _Float16 f16x8 __attribute__((ext_vector_type(8)));
typedef float    f32x4 __attribute__((ext_vector_type(4)));

#define KSA   8            // k-steps (of 32) in AGPRs (8*8t*4 = 256 AGPR, full file)
#define KSS   4            // k-steps streamed from L2 (fragment-ordered wf16)
#define KSLDS 4            // k-steps in LDS (128 KB slab)
#define NT    8            // N-tiles (16 cols) per wave
#define HSTR  520          // hbuf stride in f16 (+4-bank skew, 16B aligned)

// ---------------------------------------------------------------------------
// P[v][h] = emb[v,:] . W_ih[h,:] + b_ih[h] + b_hh[h]  (f16 table, 128x512)
// ---------------------------------------------------------------------------
__global__ __launch_bounds__(256) void prep_P(
    const float* __restrict__ emb, const float* __restrict__ W_ih,
    const float* __restrict__ b_ih, const float* __restrict__ b_hh,
    f16* __restrict__ P)
{
    __shared__ float er[4][EE];
    const int v0 = blockIdx.x * 4;
    for (int i = threadIdx.x; i < 4 * EE; i += 256)
        er[i >> 8][i & 255] = emb[(size_t)v0 * EE + i];
    __syncthreads();
    for (int h = threadIdx.x; h < HH; h += 256) {
        const float4* wr = (const float4*)(W_ih + (size_t)h * EE);
        float s0 = 0.f, s1 = 0.f, s2 = 0.f, s3 = 0.f;
        #pragma unroll 4
        for (int e4 = 0; e4 < EE / 4; ++e4) {
            float4 w = wr[e4];
            const float* e0 = &er[0][e4 * 4];
            const float* e1 = &er[1][e4 * 4];
            const float* e2 = &er[2][e4 * 4];
            const float* e3 = &er[3][e4 * 4];
            s0 += w.x * e0[0] + w.y * e0[1] + w.z * e0[2] + w.w * e0[3];
            s1 += w.x * e1[0] + w.y * e1[1] + w.z * e1[2] + w.w * e1[3];
            s2 += w.x * e2[0] + w.y * e2[1] + w.z * e2[2] + w.w * e2[3];
            s3 += w.x * e3[0] + w.y * e3[1] + w.z * e3[2] + w.w * e3[3];
        }
        const float bias = b_ih[h] + b_hh[h];
        P[(size_t)(v0 + 0) * HH + h] = (f16)(s0 + bias);
        P[(size_t)(v0 + 1) * HH + h] = (f16)(s1 + bias);
        P[(size_t)(v0 + 2) * HH + h] = (f16)(s2 + bias);
        P[(size_t)(v0 + 3) * HH + h] = (f16)(s3 + bias);
    }
}

// ---------------------------------------------------------------------------
// prep_W: W_hh fp32 -> fragment-ordered f16 (512 KB).
// Layout [wave][ks][t][lane] x f16x8:  idx = ((wave*16+ks)*8+t)*64+lane
// lane holds B[k][n]: n = wave*128 + t*16 + (lane&15), k = ks*32 + (lane>>4)*8 + j
// ---------------------------------------------------------------------------
__global__ __launch_bounds__(64) void prep_W(
    const float* __restrict__ W_hh, f16* __restrict__ wf16)
{
    const int b    = blockIdx.x;        // ((wave*16+ks)*8+t), 512 blocks
    const int lane = threadIdx.x;
    const int wave = b >> 7;
    const int ks   = (b >> 3) & 15;
    const int t    = b & 7;
    const int n = wave * 128 + t * 16 + (lane & 15);
    const int k = ks * 32 + (lane >> 4) * 8;
    const float* wr = W_hh + (size_t)n * HH + k;
    float4 x0 = *(const float4*)(wr);
    float4 x1 = *(const float4*)(wr + 4);
    f16x8 o;
    o[0] = (f16)x0.x; o[1] = (f16)x0.y; o[2] = (f16)x0.z; o[3] = (f16)x0.w;
    o[4] = (f16)x1.x; o[5] = (f16)x1.y; o[6] = (f16)x1.z; o[7] = (f16)x1.w;
    *(f16x8*)(wf16 + (((size_t)b * 64 + lane) << 3)) = o;
}

// ---------------------------------------------------------------------------
// Fused RNN + MLP head. 64 blocks x 256 threads (4 waves, 1 wave/SIMD).
// Block owns 16 batch rows, all 512 h-cols. Wave w owns cols [128w,128w+128).
// W split per lane: ks 0..7 in AGPRs (builtin MFMA + "+a" pin at def — the
// R5/R6-proven-correct pattern; MFMA reads AGPR B operands natively),
// ks 8..11 streamed from wf16 each step (L2-hot coalesced dwordx4),
// ks 12..15 LDS slab. P enters as the accumulator init.
// MLP1 + logits fused as tail.
// ---------------------------------------------------------------------------
__global__ __launch_bounds__(256, 1) void rnn_fused(
    const int* __restrict__ x_in, const int* __restrict__ x_lens,
    const f16* __restrict__ wf16, const f16* __restrict__ P,
    const float* __restrict__ W1, const float* __restrict__ b1,
    const float* __restrict__ W2, const float* __restrict__ b2,
    f16* __restrict__ last, float* __restrict__ out)
{
    __shared__ __align__(16) f16 hbuf[16 * HSTR];                    // 16.6 KB
    __shared__ __align__(16) f16 wlds[4 * KSLDS * NT * 64 * 8];      // 128 KB
    __shared__ int xin[16 * SS];                                     // 4 KB

    const int tid  = threadIdx.x;
    const int r0   = blockIdx.x * 16;
    const int wave = tid >> 6;
    const int lane = tid & 63;
    const int lrow = lane & 15;
    const int quad = lane >> 4;
    const int n0w  = wave * 128;

    // ---- setup: bA (AGPR) from wf16; wlds fill; h0=0; tokens; lens ----
    f16x8 bA[NT][KSA];
    #pragma unroll
    for (int ks = 0; ks < KSA; ++ks)
        #pragma unroll
        for (int t = 0; t < NT; ++t) {
            f16x8 b = *(const f16x8*)(wf16 +
                (((size_t)((wave * 16 + ks) * NT + t) * 64 + lane) << 3));
            asm volatile("" : "+a"(b));   // pin this value into the AGPR file
            bA[t][ks] = b;
        }
    #pragma unroll
    for (int ksl = 0; ksl < KSLDS; ++ksl)
        #pragma unroll
        for (int t = 0; t < NT; ++t)
            *(f16x8*)(wlds + ((((wave * KSLDS + ksl) * NT + t) * 64 + lane) << 3)) =
                *(const f16x8*)(wf16 +
                    (((size_t)((wave * 16 + (KSA + KSS + ksl)) * NT + t) * 64 + lane) << 3));

    for (int i = tid; i < 16 * HSTR; i += 256) hbuf[i] = (f16)0.f;
    ((int4*)xin)[tid] = ((const int4*)(x_in + (size_t)r0 * SS))[tid];
    int lens_r[4];
    #pragma unroll
    for (int r = 0; r < 4; ++r) lens_r[r] = x_lens[r0 + quad * 4 + r];
    __syncthreads();

    const f16* arow = hbuf + lrow * HSTR + quad * 8;

    #pragma unroll 1
    for (int st = 0; st < SS; ++st) {
        // ---- acc init = P rows (scattered ushort, L2-hot; 4 base addrs) ----
        f32x4 acc[NT];
        {
            const f16* pb[4];
            #pragma unroll
            for (int r = 0; r < 4; ++r)
                pb[r] = P + (size_t)xin[(quad * 4 + r) * SS + st] * HH + n0w + lrow;
            #pragma unroll
            for (int t = 0; t < NT; ++t)
                #pragma unroll
                for (int r = 0; r < 4; ++r)
                    acc[t][r] = (float)pb[r][16 * t];
        }

        // ---- MFMA chain, K=512, with interleaved L2 stream of ks 8..11 ----
        f16x8 s8[NT], s9[NT], s10[NT], s11[NT];
        #define LOADS(arr, ks_) _Pragma("unroll") \
            for (int t = 0; t < NT; ++t) \
                arr[t] = *(const f16x8*)(wf16 + \
                    (((size_t)((wave * 16 + (ks_)) * NT + t) * 64 + lane) << 3));
        #define MFMA_S(arr, ks_) { \
            f16x8 a = *(const f16x8*)(arow + (ks_) * 32); \
            _Pragma("unroll") \
            for (int t = 0; t < NT; ++t) \
                acc[t] = __builtin_amdgcn_mfma_f32_16x16x32_f16(a, arr[t], acc[t], 0, 0, 0); }

        LOADS(s8, 8)
        #pragma unroll
        for (int ks = 0; ks < 4; ++ks) {
            f16x8 a = *(const f16x8*)(arow + ks * 32);
            #pragma unroll
            for (int t = 0; t < NT; ++t)
                acc[t] = __builtin_amdgcn_mfma_f32_16x16x32_f16(a, bA[t][ks], acc[t], 0, 0, 0);
        }
        LOADS(s9, 9)
        #pragma unroll
        for (int ks = 4; ks < 8; ++ks) {
            f16x8 a = *(const f16x8*)(arow + ks * 32);
            #pragma unroll
            for (int t = 0; t < NT; ++t)
                acc[t] = __builtin_amdgcn_mfma_f32_16x16x32_f16(a, bA[t][ks], acc[t], 0, 0, 0);
        }
        MFMA_S(s8, 8)
        LOADS(s10, 10)
        MFMA_S(s9, 9)
        LOADS(s11, 11)
        #pragma unroll
        for (int ksl = 0; ksl < KSLDS; ++ksl) {
            f16x8 a = *(const f16x8*)(arow + (KSA + KSS + ksl) * 32);
            #pragma unroll
            for (int t = 0; t < NT; ++t) {
                f16x8 b = *(const f16x8*)(wlds +
                    ((((wave * KSLDS + ksl) * NT + t) * 64 + lane) << 3));
                acc[t] = __builtin_amdgcn_mfma_f32_16x16x32_f16(a, b, acc[t], 0, 0, 0);
            }
        }
        MFMA_S(s10, 10)
        MFMA_S(s11, 11)
        #undef LOADS
        #undef MFMA_S

        __syncthreads();  // all waves done reading hbuf for this step

        // ---- epilogue: h = tanh(acc); C layout col=lrow+16t, row=quad*4+r ----
        const int tp1 = st + 1;
        #pragma unroll
        for (int t = 0; t < NT; ++t) {
            const int col = n0w + 16 * t + lrow;
            #pragma unroll
            for (int r = 0; r < 4; ++r) {
                const int row = quad * 4 + r;
                float e = __expf(2.f * acc[t][r]);   // saturates at +-inf
                f16 h16 = (f16)(1.f - 2.f / (e + 1.f));
                hbuf[row * HSTR + col] = h16;
                if (lens_r[r] == tp1)
                    last[(size_t)(r0 + row) * HH + col] = h16;
            }
        }

        __syncthreads();
    }

    // ======================= MLP head (fused tail) =========================
    for (int i = tid; i < 16 * (HH / 8); i += 256) {
        const int row = i >> 6;
        const int c8  = (i & 63) * 8;
        *(float4*)(hbuf + row * HSTR + c8) =
            *(const float4*)(last + (size_t)(r0 + row) * HH + c8);
    }
    __syncthreads();

    // ---- MLP1: hidden = relu(last @ W1^T + b1), W1 streamed from L2 ----
    {
        f32x4 macc[NT];
        #pragma unroll
        for (int t = 0; t < NT; ++t) macc[t] = (f32x4){0.f, 0.f, 0.f, 0.f};
        #pragma unroll
        for (int ks = 0; ks < 16; ++ks) {
            f16x8 a = *(const f16x8*)(arow + ks * 32);
            #pragma unroll
            for (int t = 0; t < NT; ++t) {
                const float* wr = W1 + (size_t)(n0w + 16 * t + lrow) * HH + quad * 8 + ks * 32;
                float4 x0 = *(const float4*)(wr);
                float4 x1 = *(const float4*)(wr + 4);
                f16x8 b;
                b[0] = (f16)x0.x; b[1] = (f16)x0.y; b[2] = (f16)x0.z; b[3] = (f16)x0.w;
                b[4] = (f16)x1.x; b[5] = (f16)x1.y; b[6] = (f16)x1.z; b[7] = (f16)x1.w;
                macc[t] = __builtin_amdgcn_mfma_f32_16x16x32_f16(a, b, macc[t], 0, 0, 0);
            }
        }
        __syncthreads();  // done reading hbuf; wlds dead -> reuse as hidden
        #pragma unroll
        for (int t = 0; t < NT; ++t) {
            const int col = n0w + 16 * t + lrow;
            const float bb = b1[col];
            #pragma unroll
            for (int r = 0; r < 4; ++r) {
                const int row = quad * 4 + r;
                wlds[row * HSTR + col] = (f16)fmaxf(macc[t][r] + bb, 0.f);
            }
        }
    }
    __syncthreads();

    // ---- logits = hidden @ W2^T + b2 (16x32, K=512): waves 0,1 ----
    if (wave < 2) {
        f32x4 lacc = {0.f, 0.f, 0.f, 0.f};
        const f16* hrow = wlds + lrow * HSTR + quad * 8;
        const float* wr2 = W2 + (size_t)(wave * 16 + lrow) * HH + quad * 8;
        #pragma unroll
        for (int ks = 0; ks < 16; ++ks) {
            f16x8 a = *(const f16x8*)(hrow + ks * 32);
            float4 x0 = *(const float4*)(wr2 + ks * 32);
            float4 x1 = *(const float4*)(wr2 + ks * 32 + 4);
            f16x8 b;
            b[0] = (f16)x0.x; b[1] = (f16)x0.y; b[2] = (f16)x0.z; b[3] = (f16)x0.w;
            b[4] = (f16)x1.x; b[5] = (f16)x1.y; b[6] = (f16)x1.z; b[7] = (f16)x1.w;
            lacc = __builtin_amdgcn_mfma_f32_16x16x32_f16(a, b, lacc, 0, 0, 0);
        }
        const int col = wave * 16 + lrow;
        const float bb = b2[col];
        #pragma unroll
        for (int r = 0; r < 4; ++r) {
            const int row = quad * 4 + r;
            out[(size_t)(r0 + row) * CC + col] = lacc[r] + bb;
        }
    }
}

// ---------------------------------------------------------------------------
extern "C" void kernel_launch(void* const* d_in, const int* in_sizes, int n_in,
                              void* d_out, int out_size, void* d_ws, size_t ws_size,
                              hipStream_t stream)
{
    const int*   x_in   = (const int*)d_in[0];
    const int*   x_lens = (const int*)d_in[1];
    const float* emb    = (const float*)d_in[2];
    const float* W_ih   = (const float*)d_in[3];
    const float* b_ih   = (const float*)d_in[4];
    const float* W_hh   = (const float*)d_in[5];
    const float* b_hh   = (const float*)d_in[6];
    const float* W1     = (const float*)d_in[7];
    const float* b1     = (const float*)d_in[8];
    const float* W2     = (const float*)d_in[9];
    const float* b2     = (const float*)d_in[10];
    float* out = (float*)d_out;

    // workspace carve (re-poisoned every launch; everything rewritten below)
    char* ws = (char*)d_ws;
    f16* P    = (f16*)ws;                               // 128 KiB (slot 256 KiB)
    f16* wf16 = (f16*)(ws + (256 << 10));               // 512 KiB
    f16* last = (f16*)(ws + (256 << 10) + (512 << 10)); // 1 MiB

    hipLaunchKernelGGL(prep_P, dim3(VV / 4), dim3(256), 0, stream,
                       emb, W_ih, b_ih, b_hh, P);
    hipLaunchKernelGGL(prep_W, dim3(512), dim3(64), 0, stream, W_hh, wf16);
    hipLaunchKernelGGL(rnn_fused, dim3(BB / 16), dim3(256), 0, stream,
                       x_in, x_lens, wf16, P, W1, b1, W2, b2, last, out);
}